// Round 13
// baseline (390.442 us; speedup 1.0000x reference)
//
#include <hip/hip_runtime.h>

#define NSEG 40000
#define NREG 1000
#define NEDGE 640000
#define HID 256
#define KCAT 1280   // 5 * HID
#define KP1 1024    // padded K stride for Pt (cols 1000..1023 zero)
#define LPAD 40     // LDS row stride (bf16) for gemm1 tiles
#define NBLK 157    // ceil(NSEG/256)

typedef float f32x4 __attribute__((ext_vector_type(4)));
typedef float f32x2 __attribute__((ext_vector_type(2)));
typedef short s16x8 __attribute__((ext_vector_type(8)));
typedef unsigned short u16x4 __attribute__((ext_vector_type(4)));
typedef unsigned short u16x8 __attribute__((ext_vector_type(8)));
typedef unsigned int u32x2 __attribute__((ext_vector_type(2)));

typedef __attribute__((address_space(3))) unsigned int lds_u32;
typedef __attribute__((address_space(1))) const unsigned int glb_u32;

__device__ __forceinline__ void dma16(const void* g, void* l) {
    // per-lane GLOBAL src; wave-uniform LDS base, HW writes lane i at base+i*16.
    __builtin_amdgcn_global_load_lds((glb_u32*)g, (lds_u32*)l, 16, 0, 0);
}

__device__ __forceinline__ unsigned short f2bf(float f) {
    unsigned u = __builtin_bit_cast(unsigned, f);
    u += 0x7FFFu + ((u >> 16) & 1u);   // round-to-nearest-even
    return (unsigned short)(u >> 16);
}
__device__ __forceinline__ float bf2f(unsigned short h) {
    unsigned u = ((unsigned)h) << 16;
    return __builtin_bit_cast(float, u);
}
__device__ __forceinline__ unsigned char f2fp8(float v) {
    return (unsigned char)__builtin_amdgcn_cvt_pk_fp8_f32(v, v, 0, false);
}

__device__ __forceinline__ f32x4 mfma16(s16x8 a, s16x8 b, f32x4 c) {
    return __builtin_amdgcn_mfma_f32_16x16x32_bf16(a, b, c, 0, 0, 0);
}
__device__ __forceinline__ f32x4 mfma8(long a, long b, f32x4 c) {
    return __builtin_amdgcn_mfma_f32_16x16x32_fp8_fp8(a, b, c, 0, 0, 0);
}

// ---------------------------------------------------------------- edge dtype
__global__ void detect_kernel(const unsigned int* __restrict__ E, int* flag) {
    int lane = threadIdx.x;
    unsigned v = E[2 * lane + 1];
    unsigned long long m = __ballot(v == 0u);
    if (lane == 0) *flag = (__popcll(m) >= 48) ? 1 : 0;
}

__device__ __forceinline__ int edge_at(const void* E, int idx, int is64) {
    return is64 ? (int)((const long long*)E)[idx] : ((const int*)E)[idx];
}

// ---------------------------------------------------------------- CSR build
__global__ __launch_bounds__(256) void deg_cnt_kernel(const void* __restrict__ E,
                                                      const int* __restrict__ flag,
                                                      int* deg, int* cnt) {
    int e = blockIdx.x * 256 + threadIdx.x;
    if (e >= NEDGE) return;
    int is64 = *flag;
    int s = edge_at(E, e, is64);
    int d = edge_at(E, e + NEDGE, is64);
    if (s != d) {
        atomicAdd(&deg[s], 1);
        atomicAdd(&cnt[d], 1);
    }
}

// --- hierarchical scan (scan1 also computes dinv)
__global__ __launch_bounds__(256) void scan1_kernel(const int* __restrict__ cnt,
                                                    const int* __restrict__ deg,
                                                    float* __restrict__ dinv,
                                                    int* __restrict__ bsum) {
    __shared__ int sh[256];
    int t = threadIdx.x;
    int i = blockIdx.x * 256 + t;
    int c = (i < NSEG) ? cnt[i] : 0;
    sh[t] = c;
    if (i < NSEG) {
        int d = deg[i];
        dinv[i] = d > 0 ? rsqrtf((float)d) : 0.f;
    }
    __syncthreads();
    for (int o = 128; o > 0; o >>= 1) {
        if (t < o) sh[t] += sh[t + o];
        __syncthreads();
    }
    if (t == 0) bsum[blockIdx.x] = sh[0];
}

__global__ __launch_bounds__(256) void scan2_kernel(const int* __restrict__ bsum,
                                                    int* __restrict__ boff,
                                                    int* __restrict__ rowptr) {
    __shared__ int sh[256];
    int t = threadIdx.x;
    int v = (t < NBLK) ? bsum[t] : 0;
    sh[t] = v;
    __syncthreads();
    for (int o = 1; o < 256; o <<= 1) {
        int x = 0;
        if (t >= o) x = sh[t - o];
        __syncthreads();
        if (t >= o) sh[t] += x;
        __syncthreads();
    }
    if (t < NBLK) boff[t] = sh[t] - v;
    if (t == 255) rowptr[NSEG] = sh[255];
}

__global__ __launch_bounds__(256) void scan3_kernel(const int* __restrict__ cnt,
                                                    const int* __restrict__ boff,
                                                    int* __restrict__ rowptr,
                                                    int* __restrict__ cursor) {
    __shared__ int sh[256];
    int t = threadIdx.x;
    int i = blockIdx.x * 256 + t;
    int v = (i < NSEG) ? cnt[i] : 0;
    sh[t] = v;
    __syncthreads();
    for (int o = 1; o < 256; o <<= 1) {
        int x = 0;
        if (t >= o) x = sh[t - o];
        __syncthreads();
        if (t >= o) sh[t] += x;
        __syncthreads();
    }
    if (i < NSEG) {
        int p = boff[blockIdx.x] + sh[t] - v;
        rowptr[i] = p;
        cursor[i] = p;
    }
}

// writes fused (colidx, val-bits) 8B records
__global__ __launch_bounds__(256) void scatter_kernel(const void* __restrict__ E,
                                                      const int* __restrict__ flag,
                                                      const float* __restrict__ dinv,
                                                      int* cursor,
                                                      long long* __restrict__ colval) {
    int e = blockIdx.x * 256 + threadIdx.x;
    if (e >= NEDGE) return;
    int is64 = *flag;
    int s = edge_at(E, e, is64);
    int d = edge_at(E, e + NEDGE, is64);
    if (s != d) {
        int pos = atomicAdd(&cursor[d], 1);
        float v = -dinv[s] * dinv[d];
        colval[pos] = ((long long)(unsigned)__builtin_bit_cast(unsigned, v) << 32)
                    | (unsigned)s;
    }
}

// ---------------------------------------------------------------- weight prep (fused; adds fp8 Wt8)
__global__ void prep_w_kernel(const float* __restrict__ P, const float* __restrict__ W,
                              unsigned short* __restrict__ Pt, unsigned short* __restrict__ Wt,
                              unsigned char* __restrict__ Wt8) {
    int n = blockIdx.x;
    for (int k = threadIdx.x; k < KP1; k += blockDim.x)
        Pt[(size_t)n * KP1 + k] = (k < NREG) ? f2bf(P[(size_t)k * HID + n]) : (unsigned short)0;
    for (int k = threadIdx.x; k < KCAT; k += blockDim.x) {
        float w = W[(size_t)k * HID + n];
        Wt[(size_t)n * KCAT + k] = f2bf(w);
        Wt8[(size_t)n * KCAT + k] = f2fp8(w);
    }
}

// ---------------------------------------------------------------- GEMM1 (R9 structure + fp8 side-write)
__global__ __launch_bounds__(256) void gemm1_kernel(const float* __restrict__ S,
                                                    const unsigned short* __restrict__ Pt,
                                                    float* __restrict__ raw,
                                                    unsigned short* __restrict__ xcat,
                                                    unsigned char* __restrict__ x8) {
    __shared__ unsigned short As[64][LPAD];
    __shared__ unsigned short Bs[256][LPAD];
    const int m0 = blockIdx.x * 64;
    const int tid = threadIdx.x;
    const int lane = tid & 63, wn = tid >> 6;
    const int r = lane & 15, q = lane >> 4;
    const int srow = tid >> 2, scol = (tid & 3) * 8;

    f32x4 acc[4][4] = {};

    for (int kb = 0; kb < NREG; kb += 32) {
        const bool kvalid = (kb + scol + 8 <= NREG);  // NREG % 8 == 0
        u16x8 av = {0, 0, 0, 0, 0, 0, 0, 0};
        u16x8 bv0 = av, bv1 = av, bv2 = av, bv3 = av;
        if (kvalid) {
            const float* sp = S + (size_t)(m0 + srow) * NREG + kb + scol;
            f32x4 f0 = *(const f32x4*)sp;
            f32x4 f1 = *(const f32x4*)(sp + 4);
            av[0] = f2bf(f0[0]); av[1] = f2bf(f0[1]); av[2] = f2bf(f0[2]); av[3] = f2bf(f0[3]);
            av[4] = f2bf(f1[0]); av[5] = f2bf(f1[1]); av[6] = f2bf(f1[2]); av[7] = f2bf(f1[3]);
            bv0 = *(const u16x8*)(Pt + (size_t)(srow)       * KP1 + kb + scol);
            bv1 = *(const u16x8*)(Pt + (size_t)(srow +  64) * KP1 + kb + scol);
            bv2 = *(const u16x8*)(Pt + (size_t)(srow + 128) * KP1 + kb + scol);
            bv3 = *(const u16x8*)(Pt + (size_t)(srow + 192) * KP1 + kb + scol);
        }
        __syncthreads();
        *(u16x8*)&As[srow][scol] = av;
        *(u16x8*)&Bs[srow][scol] = bv0;
        *(u16x8*)&Bs[srow + 64][scol] = bv1;
        *(u16x8*)&Bs[srow + 128][scol] = bv2;
        *(u16x8*)&Bs[srow + 192][scol] = bv3;
        __syncthreads();
        s16x8 af[4], bfv[4];
#pragma unroll
        for (int am = 0; am < 4; ++am) af[am] = *(const s16x8*)&As[am * 16 + r][q * 8];
#pragma unroll
        for (int bn = 0; bn < 4; ++bn) bfv[bn] = *(const s16x8*)&Bs[wn * 64 + bn * 16 + r][q * 8];
#pragma unroll
        for (int am = 0; am < 4; ++am) {
#pragma unroll
            for (int bn = 0; bn < 4; ++bn)
                acc[am][bn] = mfma16(af[am], bfv[bn], acc[am][bn]);
        }
    }
#pragma unroll
    for (int am = 0; am < 4; ++am) {
        int rowb = m0 + am * 16 + q * 4;
#pragma unroll
        for (int bn = 0; bn < 4; ++bn) {
            int col = wn * 64 + bn * 16 + r;
#pragma unroll
            for (int i = 0; i < 4; ++i) {
                float v = acc[am][bn][i];
                raw[(size_t)(rowb + i) * HID + col] = v;
                xcat[(size_t)(rowb + i) * KCAT + col] = f2bf(v);
                x8[(size_t)(rowb + i) * KCAT + col] = f2fp8(v);
            }
        }
    }
}

// ---------------------------------------------------------------- propagation (half-wave, fp8 gather)
__global__ __launch_bounds__(256) void prop_kernel(unsigned short* xcat,
                                                   unsigned char* x8,
                                                   const int* __restrict__ rowptr,
                                                   const long long* __restrict__ colval,
                                                   int inOff, int outOff, int subOff,
                                                   float scale) {
    const int g = blockIdx.x * 4 + (threadIdx.x >> 6);
    const int lane = threadIdx.x & 63;
    const int half = lane >> 5;
    const int l5 = lane & 31;
    const int e0 = rowptr[g], e1 = rowptr[g + 1];
    float a0 = 0.f, a1 = 0.f, a2 = 0.f, a3 = 0.f;
    float a4 = 0.f, a5 = 0.f, a6 = 0.f, a7 = 0.f;
    const unsigned char* xin = x8 + inOff + l5 * 8;

    for (int base = e0; base < e1; base += 64) {
        int m = e1 - base;
        if (m > 64) m = 64;
        int cc = 0;
        float vv = 0.f;
        if (lane < m) {
            long long cv = colval[base + lane];
            cc = (int)(unsigned)cv;
            vv = __builtin_bit_cast(float, (unsigned)(cv >> 32));
        }
        int i = 0;
#pragma unroll 4
        for (; i + 2 <= m; i += 2) {
            int c = __shfl(cc, i + half);
            float v = __shfl(vv, i + half);
            u32x2 t = *(const u32x2*)(xin + (size_t)c * KCAT);
            f32x2 d0 = __builtin_amdgcn_cvt_pk_f32_fp8(t[0], false);
            f32x2 d1 = __builtin_amdgcn_cvt_pk_f32_fp8(t[0], true);
            f32x2 d2 = __builtin_amdgcn_cvt_pk_f32_fp8(t[1], false);
            f32x2 d3 = __builtin_amdgcn_cvt_pk_f32_fp8(t[1], true);
            a0 += v * d0[0]; a1 += v * d0[1];
            a2 += v * d1[0]; a3 += v * d1[1];
            a4 += v * d2[0]; a5 += v * d2[1];
            a6 += v * d3[0]; a7 += v * d3[1];
        }
        if (i < m) {   // odd tail: half0 handles the last edge
            int c = __shfl(cc, i);
            float v = __shfl(vv, i);
            if (half == 0) {
                u32x2 t = *(const u32x2*)(xin + (size_t)c * KCAT);
                f32x2 d0 = __builtin_amdgcn_cvt_pk_f32_fp8(t[0], false);
                f32x2 d1 = __builtin_amdgcn_cvt_pk_f32_fp8(t[0], true);
                f32x2 d2 = __builtin_amdgcn_cvt_pk_f32_fp8(t[1], false);
                f32x2 d3 = __builtin_amdgcn_cvt_pk_f32_fp8(t[1], true);
                a0 += v * d0[0]; a1 += v * d0[1];
                a2 += v * d1[0]; a3 += v * d1[1];
                a4 += v * d2[0]; a5 += v * d2[1];
                a6 += v * d3[0]; a7 += v * d3[1];
            }
        }
    }
    a0 += __shfl_xor(a0, 32); a1 += __shfl_xor(a1, 32);
    a2 += __shfl_xor(a2, 32); a3 += __shfl_xor(a3, 32);
    a4 += __shfl_xor(a4, 32); a5 += __shfl_xor(a5, 32);
    a6 += __shfl_xor(a6, 32); a7 += __shfl_xor(a7, 32);

    if (half == 0) {
        a0 *= scale; a1 *= scale; a2 *= scale; a3 *= scale;
        a4 *= scale; a5 *= scale; a6 *= scale; a7 *= scale;
        if (subOff >= 0) {   // subtraction operand stays bf16 (accurate)
            u16x8 p = *(const u16x8*)(xcat + (size_t)g * KCAT + subOff + l5 * 8);
            a0 -= bf2f(p[0]); a1 -= bf2f(p[1]); a2 -= bf2f(p[2]); a3 -= bf2f(p[3]);
            a4 -= bf2f(p[4]); a5 -= bf2f(p[5]); a6 -= bf2f(p[6]); a7 -= bf2f(p[7]);
        }
        u16x8 o = {f2bf(a0), f2bf(a1), f2bf(a2), f2bf(a3),
                   f2bf(a4), f2bf(a5), f2bf(a6), f2bf(a7)};
        *(u16x8*)(xcat + (size_t)g * KCAT + outOff + l5 * 8) = o;
        unsigned p0 = 0, p1 = 0;
        p0 = __builtin_amdgcn_cvt_pk_fp8_f32(a0, a1, (int)p0, false);
        p0 = __builtin_amdgcn_cvt_pk_fp8_f32(a2, a3, (int)p0, true);
        p1 = __builtin_amdgcn_cvt_pk_fp8_f32(a4, a5, (int)p1, false);
        p1 = __builtin_amdgcn_cvt_pk_fp8_f32(a6, a7, (int)p1, true);
        u32x2 o8 = {p0, p1};
        *(u32x2*)(x8 + (size_t)g * KCAT + outOff + l5 * 8) = o8;
    }
}

// ---------------------------------------------------------------- GEMM2 fp8 + GELU + LN
// pre = X8 @ W8 + bias (fp8 MFMA, fp32 acc); out = LN(GELU(pre)).
// BM=128 BN=256 BK=32, 512 thr, dbuf-DMA; per K-step 12 x 1KB chunks
// (8 B-chunks + 4 A-chunks), 32-B fp8 rows in LDS.
__global__ __launch_bounds__(512) void gemm2_kernel(const unsigned char* __restrict__ x8,
                                                    const unsigned char* __restrict__ Wt8,
                                                    const float* __restrict__ bias,
                                                    const float* __restrict__ gamma,
                                                    const float* __restrict__ beta,
                                                    float* __restrict__ outp) {
    __shared__ unsigned char As8[2][128 * 32];
    __shared__ unsigned char Bs8[2][256 * 32];
    __shared__ float rs[128][4];
    __shared__ float rss[128][4];
    const int tid = threadIdx.x;
    const int lane = tid & 63, wid = tid >> 6;
    const int wm = wid >> 2, wn = wid & 3;
    const int r = lane & 15, q = lane >> 4;
    const int m0 = blockIdx.x * 128;
    const int drow = lane >> 1;            // dma: 32 rows/chunk, 2 lanes/row
    const int dhalf = (lane & 1) * 16;

    f32x4 acc[4][4] = {};

    auto stage = [&](int c, int kb) {
        // B chunk = wave id (8 chunks of 32 Wt8 rows)
        {
            int n = wid * 32 + drow;
            dma16(Wt8 + (size_t)n * KCAT + kb + dhalf, &Bs8[c][wid * 1024]);
        }
        // A chunks on waves 0-3 (4 chunks of 32 x8 rows)
        if (wid < 4) {
            int row = m0 + wid * 32 + drow;   // tail reads past x8 land in ws: safe, store-guarded
            dma16(x8 + (size_t)row * KCAT + kb + dhalf, &As8[c][wid * 1024]);
        }
    };

    stage(0, 0);
    __syncthreads();

    for (int t = 0; t < 40; ++t) {
        const int c = t & 1;
        if (t < 39) stage(c ^ 1, (t + 1) * 32);
        long af[4], bfv[4];
#pragma unroll
        for (int am = 0; am < 4; ++am)
            af[am] = *(const long*)&As8[c][(wm * 64 + am * 16 + r) * 32 + q * 8];
#pragma unroll
        for (int bn = 0; bn < 4; ++bn)
            bfv[bn] = *(const long*)&Bs8[c][(wn * 64 + bn * 16 + r) * 32 + q * 8];
#pragma unroll
        for (int am = 0; am < 4; ++am)
#pragma unroll
            for (int bn = 0; bn < 4; ++bn)
                acc[am][bn] = mfma8(af[am], bfv[bn], acc[am][bn]);
        __syncthreads();
    }

    float bc[4], gm[4], bt[4];
#pragma unroll
    for (int bn = 0; bn < 4; ++bn) {
        int col = wn * 64 + bn * 16 + r;
        bc[bn] = bias[col];
        gm[bn] = gamma[col];
        bt[bn] = beta[col];
    }
#pragma unroll
    for (int am = 0; am < 4; ++am) {
#pragma unroll
        for (int i = 0; i < 4; ++i) {
            float s = 0.f, ss = 0.f;
#pragma unroll
            for (int bn = 0; bn < 4; ++bn) {
                float v = acc[am][bn][i] + bc[bn];
                v = 0.5f * v * (1.f + erff(v * 0.70710678118654752f));
                acc[am][bn][i] = v;
                s += v;
                ss += v * v;
            }
#pragma unroll
            for (int msk = 1; msk < 16; msk <<= 1) {
                s += __shfl_xor(s, msk);
                ss += __shfl_xor(ss, msk);
            }
            if (r == 0) {
                int row = wm * 64 + am * 16 + q * 4 + i;
                rs[row][wn] = s;
                rss[row][wn] = ss;
            }
        }
    }
    __syncthreads();
#pragma unroll
    for (int am = 0; am < 4; ++am) {
#pragma unroll
        for (int i = 0; i < 4; ++i) {
            int row = wm * 64 + am * 16 + q * 4 + i;
            float s = rs[row][0] + rs[row][1] + rs[row][2] + rs[row][3];
            float ss = rss[row][0] + rss[row][1] + rss[row][2] + rss[row][3];
            float mu = s * (1.f / HID);
            float var = ss * (1.f / HID) - mu * mu;
            float inv = rsqrtf(var + 1e-5f);
            if (m0 + row < NSEG) {
#pragma unroll
                for (int bn = 0; bn < 4; ++bn) {
                    int col = wn * 64 + bn * 16 + r;
                    outp[(size_t)(m0 + row) * HID + col] = (acc[am][bn][i] - mu) * inv * gm[bn] + bt[bn];
                }
            }
        }
    }
}

// ---------------------------------------------------------------- launch
extern "C" void kernel_launch(void* const* d_in, const int* in_sizes, int n_in,
                              void* d_out, int out_size, void* d_ws, size_t ws_size,
                              hipStream_t stream) {
    const float* P     = (const float*)d_in[0];
    const float* S     = (const float*)d_in[1];
    const void*  E     = d_in[2];
    const float* W     = (const float*)d_in[3];
    const float* bias  = (const float*)d_in[4];
    const float* gamma = (const float*)d_in[5];
    const float* beta  = (const float*)d_in[6];

    float* out = (float*)d_out;            // seg_low [40000*256]
    float* raw = out + (size_t)NSEG * HID; // seg_low_raw [40000*256]

    char* ws = (char*)d_ws;
    size_t off = 0;
    auto alloc = [&](size_t bytes) -> void* {
        void* p = ws + off;
        off += (bytes + 255) & ~(size_t)255;
        return p;
    };
    unsigned short* xcat   = (unsigned short*)alloc((size_t)NSEG * KCAT * 2);
    unsigned char*  x8     = (unsigned char*)alloc((size_t)NSEG * KCAT);
    unsigned short* Pt     = (unsigned short*)alloc((size_t)HID * KP1 * 2);
    unsigned short* Wt     = (unsigned short*)alloc((size_t)HID * KCAT * 2);
    unsigned char*  Wt8    = (unsigned char*)alloc((size_t)HID * KCAT);
    int*            deg    = (int*)alloc((size_t)NSEG * 4);
    float*          dinv   = (float*)alloc((size_t)NSEG * 4);
    int*            cnt    = (int*)alloc((size_t)NSEG * 4);
    int*            rowptr = (int*)alloc((size_t)(NSEG + 1) * 4);
    int*            cursor = (int*)alloc((size_t)NSEG * 4);
    long long*      colval = (long long*)alloc((size_t)NEDGE * 8);
    int*            bsum   = (int*)alloc((size_t)NBLK * 4);
    int*            boff   = (int*)alloc((size_t)NBLK * 4);
    int*            flag   = (int*)alloc(256);
    if (off > ws_size) return;

    hipMemsetAsync(deg, 0, (size_t)NSEG * 4, stream);
    hipMemsetAsync(cnt, 0, (size_t)NSEG * 4, stream);

    detect_kernel<<<1, 64, 0, stream>>>((const unsigned int*)E, flag);
    prep_w_kernel<<<HID, 256, 0, stream>>>(P, W, Pt, Wt, Wt8);

    deg_cnt_kernel<<<NEDGE / 256, 256, 0, stream>>>(E, flag, deg, cnt);
    scan1_kernel<<<NBLK, 256, 0, stream>>>(cnt, deg, dinv, bsum);
    scan2_kernel<<<1, 256, 0, stream>>>(bsum, boff, rowptr);
    scan3_kernel<<<NBLK, 256, 0, stream>>>(cnt, boff, rowptr, cursor);
    scatter_kernel<<<NEDGE / 256, 256, 0, stream>>>(E, flag, dinv, cursor, colval);

    gemm1_kernel<<<NSEG / 64, 256, 0, stream>>>(S, Pt, raw, xcat, x8);

    prop_kernel<<<NSEG / 4, 256, 0, stream>>>(xcat, x8, rowptr, colval, 0 * HID, 1 * HID, -1, 1.f);
    prop_kernel<<<NSEG / 4, 256, 0, stream>>>(xcat, x8, rowptr, colval, 1 * HID, 2 * HID, 0 * HID, 2.f);
    prop_kernel<<<NSEG / 4, 256, 0, stream>>>(xcat, x8, rowptr, colval, 2 * HID, 3 * HID, 1 * HID, 2.f);
    prop_kernel<<<NSEG / 4, 256, 0, stream>>>(xcat, x8, rowptr, colval, 3 * HID, 4 * HID, 2 * HID, 2.f);

    gemm2_kernel<<<(NSEG + 127) / 128, 512, 0, stream>>>(x8, Wt8, bias, gamma, beta, out);
}

// Round 14
// 383.747 us; speedup vs baseline: 1.0174x; 1.0174x over previous
//
#include <hip/hip_runtime.h>

#define NSEG 40000
#define NREG 1000
#define NEDGE 640000
#define HID 256
#define KCAT 1280   // 5 * HID
#define KP1 1024    // padded K stride for Pt (cols 1000..1023 zero)
#define LP2 72      // LDS row stride (bf16) for 64-col gemm1 tiles
#define NBLK 157    // ceil(NSEG/256)

typedef float f32x4 __attribute__((ext_vector_type(4)));
typedef float f32x2 __attribute__((ext_vector_type(2)));
typedef short s16x8 __attribute__((ext_vector_type(8)));
typedef unsigned short u16x4 __attribute__((ext_vector_type(4)));
typedef unsigned short u16x8 __attribute__((ext_vector_type(8)));
typedef unsigned int u32x2 __attribute__((ext_vector_type(2)));

typedef __attribute__((address_space(3))) unsigned int lds_u32;
typedef __attribute__((address_space(1))) const unsigned int glb_u32;

__device__ __forceinline__ void dma16(const void* g, void* l) {
    // per-lane GLOBAL src; wave-uniform LDS base, HW writes lane i at base+i*16.
    __builtin_amdgcn_global_load_lds((glb_u32*)g, (lds_u32*)l, 16, 0, 0);
}

__device__ __forceinline__ unsigned short f2bf(float f) {
    unsigned u = __builtin_bit_cast(unsigned, f);
    u += 0x7FFFu + ((u >> 16) & 1u);   // round-to-nearest-even
    return (unsigned short)(u >> 16);
}
__device__ __forceinline__ float bf2f(unsigned short h) {
    unsigned u = ((unsigned)h) << 16;
    return __builtin_bit_cast(float, u);
}
__device__ __forceinline__ unsigned char f2fp8(float v) {
    return (unsigned char)__builtin_amdgcn_cvt_pk_fp8_f32(v, v, 0, false);
}

__device__ __forceinline__ f32x4 mfma16(s16x8 a, s16x8 b, f32x4 c) {
    return __builtin_amdgcn_mfma_f32_16x16x32_bf16(a, b, c, 0, 0, 0);
}
__device__ __forceinline__ f32x4 mfma8(long a, long b, f32x4 c) {
    return __builtin_amdgcn_mfma_f32_16x16x32_fp8_fp8(a, b, c, 0, 0, 0);
}

// ---------------------------------------------------------------- edge dtype
__global__ void detect_kernel(const unsigned int* __restrict__ E, int* flag) {
    int lane = threadIdx.x;
    unsigned v = E[2 * lane + 1];
    unsigned long long m = __ballot(v == 0u);
    if (lane == 0) *flag = (__popcll(m) >= 48) ? 1 : 0;
}

__device__ __forceinline__ int edge_at(const void* E, int idx, int is64) {
    return is64 ? (int)((const long long*)E)[idx] : ((const int*)E)[idx];
}

// ---------------------------------------------------------------- CSR build
__global__ __launch_bounds__(256) void deg_cnt_kernel(const void* __restrict__ E,
                                                      const int* __restrict__ flag,
                                                      int* deg, int* cnt) {
    int e = blockIdx.x * 256 + threadIdx.x;
    if (e >= NEDGE) return;
    int is64 = *flag;
    int s = edge_at(E, e, is64);
    int d = edge_at(E, e + NEDGE, is64);
    if (s != d) {
        atomicAdd(&deg[s], 1);
        atomicAdd(&cnt[d], 1);
    }
}

// --- hierarchical scan (scan1 also computes dinv)
__global__ __launch_bounds__(256) void scan1_kernel(const int* __restrict__ cnt,
                                                    const int* __restrict__ deg,
                                                    float* __restrict__ dinv,
                                                    int* __restrict__ bsum) {
    __shared__ int sh[256];
    int t = threadIdx.x;
    int i = blockIdx.x * 256 + t;
    int c = (i < NSEG) ? cnt[i] : 0;
    sh[t] = c;
    if (i < NSEG) {
        int d = deg[i];
        dinv[i] = d > 0 ? rsqrtf((float)d) : 0.f;
    }
    __syncthreads();
    for (int o = 128; o > 0; o >>= 1) {
        if (t < o) sh[t] += sh[t + o];
        __syncthreads();
    }
    if (t == 0) bsum[blockIdx.x] = sh[0];
}

__global__ __launch_bounds__(256) void scan2_kernel(const int* __restrict__ bsum,
                                                    int* __restrict__ boff,
                                                    int* __restrict__ rowptr) {
    __shared__ int sh[256];
    int t = threadIdx.x;
    int v = (t < NBLK) ? bsum[t] : 0;
    sh[t] = v;
    __syncthreads();
    for (int o = 1; o < 256; o <<= 1) {
        int x = 0;
        if (t >= o) x = sh[t - o];
        __syncthreads();
        if (t >= o) sh[t] += x;
        __syncthreads();
    }
    if (t < NBLK) boff[t] = sh[t] - v;
    if (t == 255) rowptr[NSEG] = sh[255];
}

__global__ __launch_bounds__(256) void scan3_kernel(const int* __restrict__ cnt,
                                                    const int* __restrict__ boff,
                                                    int* __restrict__ rowptr,
                                                    int* __restrict__ cursor) {
    __shared__ int sh[256];
    int t = threadIdx.x;
    int i = blockIdx.x * 256 + t;
    int v = (i < NSEG) ? cnt[i] : 0;
    sh[t] = v;
    __syncthreads();
    for (int o = 1; o < 256; o <<= 1) {
        int x = 0;
        if (t >= o) x = sh[t - o];
        __syncthreads();
        if (t >= o) sh[t] += x;
        __syncthreads();
    }
    if (i < NSEG) {
        int p = boff[blockIdx.x] + sh[t] - v;
        rowptr[i] = p;
        cursor[i] = p;
    }
}

// writes fused (colidx, val-bits) 8B records
__global__ __launch_bounds__(256) void scatter_kernel(const void* __restrict__ E,
                                                      const int* __restrict__ flag,
                                                      const float* __restrict__ dinv,
                                                      int* cursor,
                                                      long long* __restrict__ colval) {
    int e = blockIdx.x * 256 + threadIdx.x;
    if (e >= NEDGE) return;
    int is64 = *flag;
    int s = edge_at(E, e, is64);
    int d = edge_at(E, e + NEDGE, is64);
    if (s != d) {
        int pos = atomicAdd(&cursor[d], 1);
        float v = -dinv[s] * dinv[d];
        colval[pos] = ((long long)(unsigned)__builtin_bit_cast(unsigned, v) << 32)
                    | (unsigned)s;
    }
}

// ---------------------------------------------------------------- weight prep (fused; adds fp8 Wt8)
__global__ void prep_w_kernel(const float* __restrict__ P, const float* __restrict__ W,
                              unsigned short* __restrict__ Pt, unsigned char* __restrict__ Wt8) {
    int n = blockIdx.x;
    for (int k = threadIdx.x; k < KP1; k += blockDim.x)
        Pt[(size_t)n * KP1 + k] = (k < NREG) ? f2bf(P[(size_t)k * HID + n]) : (unsigned short)0;
    for (int k = threadIdx.x; k < KCAT; k += blockDim.x)
        Wt8[(size_t)n * KCAT + k] = f2fp8(W[(size_t)k * HID + n]);
}

// ---------------------------------------------------------------- GEMM1 (BK=64, 16 iters)
// raw = S @ P ; bf16 + fp8 copies into Xcat/X8 seg 0.
// BM=64 BN=256 BK=64, 256 thr (4 waves over N), 2-barrier single-buffer.
__global__ __launch_bounds__(256) void gemm1_kernel(const float* __restrict__ S,
                                                    const unsigned short* __restrict__ Pt,
                                                    float* __restrict__ raw,
                                                    unsigned short* __restrict__ xcat,
                                                    unsigned char* __restrict__ x8) {
    __shared__ unsigned short As[64][LP2];
    __shared__ unsigned short Bs[256][LP2];
    const int m0 = blockIdx.x * 64;
    const int tid = threadIdx.x;
    const int lane = tid & 63, wn = tid >> 6;
    const int r = lane & 15, q = lane >> 4;
    const int srow = tid >> 2, scol = (tid & 3) * 16;
    const float* aptr = S + (size_t)(m0 + srow) * NREG;

    f32x4 acc[4][4] = {};

    for (int kb = 0; kb < KP1; kb += 64) {
        // A: two 8-col chunks, clamped into valid S (garbage x B-pad-zero = 0)
        int ka0 = kb + scol;     if (ka0 + 8 > NREG) ka0 = 0;
        int ka1 = kb + scol + 8; if (ka1 + 8 > NREG) ka1 = 0;
        f32x4 f0 = *(const f32x4*)(aptr + ka0);
        f32x4 f1 = *(const f32x4*)(aptr + ka0 + 4);
        f32x4 f2 = *(const f32x4*)(aptr + ka1);
        f32x4 f3 = *(const f32x4*)(aptr + ka1 + 4);
        // B: 4 row-groups x two 8-col chunks (Pt zero-padded to KP1: always safe)
        u16x8 bv[4][2];
#pragma unroll
        for (int j = 0; j < 4; ++j) {
            const unsigned short* bp = Pt + (size_t)(j * 64 + srow) * KP1 + kb + scol;
            bv[j][0] = *(const u16x8*)(bp);
            bv[j][1] = *(const u16x8*)(bp + 8);
        }
        __syncthreads();
        {
            u16x8 a0 = {f2bf(f0[0]), f2bf(f0[1]), f2bf(f0[2]), f2bf(f0[3]),
                        f2bf(f1[0]), f2bf(f1[1]), f2bf(f1[2]), f2bf(f1[3])};
            u16x8 a1 = {f2bf(f2[0]), f2bf(f2[1]), f2bf(f2[2]), f2bf(f2[3]),
                        f2bf(f3[0]), f2bf(f3[1]), f2bf(f3[2]), f2bf(f3[3])};
            *(u16x8*)&As[srow][scol] = a0;
            *(u16x8*)&As[srow][scol + 8] = a1;
        }
#pragma unroll
        for (int j = 0; j < 4; ++j) {
            *(u16x8*)&Bs[j * 64 + srow][scol] = bv[j][0];
            *(u16x8*)&Bs[j * 64 + srow][scol + 8] = bv[j][1];
        }
        __syncthreads();
        s16x8 af[4][2], bfv[4][2];
#pragma unroll
        for (int am = 0; am < 4; ++am) {
            af[am][0] = *(const s16x8*)&As[am * 16 + r][q * 8];
            af[am][1] = *(const s16x8*)&As[am * 16 + r][32 + q * 8];
        }
#pragma unroll
        for (int bn = 0; bn < 4; ++bn) {
            bfv[bn][0] = *(const s16x8*)&Bs[wn * 64 + bn * 16 + r][q * 8];
            bfv[bn][1] = *(const s16x8*)&Bs[wn * 64 + bn * 16 + r][32 + q * 8];
        }
#pragma unroll
        for (int kk = 0; kk < 2; ++kk)
#pragma unroll
            for (int am = 0; am < 4; ++am)
#pragma unroll
                for (int bn = 0; bn < 4; ++bn)
                    acc[am][bn] = mfma16(af[am][kk], bfv[bn][kk], acc[am][bn]);
    }
#pragma unroll
    for (int am = 0; am < 4; ++am) {
        int rowb = m0 + am * 16 + q * 4;
#pragma unroll
        for (int bn = 0; bn < 4; ++bn) {
            int col = wn * 64 + bn * 16 + r;
#pragma unroll
            for (int i = 0; i < 4; ++i) {
                float v = acc[am][bn][i];
                raw[(size_t)(rowb + i) * HID + col] = v;
                xcat[(size_t)(rowb + i) * KCAT + col] = f2bf(v);
                x8[(size_t)(rowb + i) * KCAT + col] = f2fp8(v);
            }
        }
    }
}

// ---------------------------------------------------------------- propagation (half-wave, fp8 gather)
__global__ __launch_bounds__(256) void prop_kernel(unsigned short* xcat,
                                                   unsigned char* x8,
                                                   const int* __restrict__ rowptr,
                                                   const long long* __restrict__ colval,
                                                   int inOff, int outOff, int subOff,
                                                   float scale, int writeBf16) {
    const int g = blockIdx.x * 4 + (threadIdx.x >> 6);
    const int lane = threadIdx.x & 63;
    const int half = lane >> 5;
    const int l5 = lane & 31;
    const int e0 = rowptr[g], e1 = rowptr[g + 1];
    float a0 = 0.f, a1 = 0.f, a2 = 0.f, a3 = 0.f;
    float a4 = 0.f, a5 = 0.f, a6 = 0.f, a7 = 0.f;
    const unsigned char* xin = x8 + inOff + l5 * 8;

    for (int base = e0; base < e1; base += 64) {
        int m = e1 - base;
        if (m > 64) m = 64;
        int cc = 0;
        float vv = 0.f;
        if (lane < m) {
            long long cv = colval[base + lane];
            cc = (int)(unsigned)cv;
            vv = __builtin_bit_cast(float, (unsigned)(cv >> 32));
        }
        int i = 0;
#pragma unroll 4
        for (; i + 2 <= m; i += 2) {
            int c = __shfl(cc, i + half);
            float v = __shfl(vv, i + half);
            u32x2 t = *(const u32x2*)(xin + (size_t)c * KCAT);
            f32x2 d0 = __builtin_amdgcn_cvt_pk_f32_fp8(t[0], false);
            f32x2 d1 = __builtin_amdgcn_cvt_pk_f32_fp8(t[0], true);
            f32x2 d2 = __builtin_amdgcn_cvt_pk_f32_fp8(t[1], false);
            f32x2 d3 = __builtin_amdgcn_cvt_pk_f32_fp8(t[1], true);
            a0 += v * d0[0]; a1 += v * d0[1];
            a2 += v * d1[0]; a3 += v * d1[1];
            a4 += v * d2[0]; a5 += v * d2[1];
            a6 += v * d3[0]; a7 += v * d3[1];
        }
        if (i < m) {   // odd tail: half0 handles the last edge
            int c = __shfl(cc, i);
            float v = __shfl(vv, i);
            if (half == 0) {
                u32x2 t = *(const u32x2*)(xin + (size_t)c * KCAT);
                f32x2 d0 = __builtin_amdgcn_cvt_pk_f32_fp8(t[0], false);
                f32x2 d1 = __builtin_amdgcn_cvt_pk_f32_fp8(t[0], true);
                f32x2 d2 = __builtin_amdgcn_cvt_pk_f32_fp8(t[1], false);
                f32x2 d3 = __builtin_amdgcn_cvt_pk_f32_fp8(t[1], true);
                a0 += v * d0[0]; a1 += v * d0[1];
                a2 += v * d1[0]; a3 += v * d1[1];
                a4 += v * d2[0]; a5 += v * d2[1];
                a6 += v * d3[0]; a7 += v * d3[1];
            }
        }
    }
    a0 += __shfl_xor(a0, 32); a1 += __shfl_xor(a1, 32);
    a2 += __shfl_xor(a2, 32); a3 += __shfl_xor(a3, 32);
    a4 += __shfl_xor(a4, 32); a5 += __shfl_xor(a5, 32);
    a6 += __shfl_xor(a6, 32); a7 += __shfl_xor(a7, 32);

    if (half == 0) {
        a0 *= scale; a1 *= scale; a2 *= scale; a3 *= scale;
        a4 *= scale; a5 *= scale; a6 *= scale; a7 *= scale;
        if (subOff >= 0) {   // subtraction operand stays bf16 (accurate)
            u16x8 p = *(const u16x8*)(xcat + (size_t)g * KCAT + subOff + l5 * 8);
            a0 -= bf2f(p[0]); a1 -= bf2f(p[1]); a2 -= bf2f(p[2]); a3 -= bf2f(p[3]);
            a4 -= bf2f(p[4]); a5 -= bf2f(p[5]); a6 -= bf2f(p[6]); a7 -= bf2f(p[7]);
        }
        if (writeBf16) {
            u16x8 o = {f2bf(a0), f2bf(a1), f2bf(a2), f2bf(a3),
                       f2bf(a4), f2bf(a5), f2bf(a6), f2bf(a7)};
            *(u16x8*)(xcat + (size_t)g * KCAT + outOff + l5 * 8) = o;
        }
        unsigned p0 = 0, p1 = 0;
        p0 = __builtin_amdgcn_cvt_pk_fp8_f32(a0, a1, (int)p0, false);
        p0 = __builtin_amdgcn_cvt_pk_fp8_f32(a2, a3, (int)p0, true);
        p1 = __builtin_amdgcn_cvt_pk_fp8_f32(a4, a5, (int)p1, false);
        p1 = __builtin_amdgcn_cvt_pk_fp8_f32(a6, a7, (int)p1, true);
        u32x2 o8 = {p0, p1};
        *(u32x2*)(x8 + (size_t)g * KCAT + outOff + l5 * 8) = o8;
    }
}

// ---------------------------------------------------------------- GEMM2 fp8 BK=64 (20 iters) + GELU + LN
// BM=128 BN=256 BK=64, 512 thr, dbuf-DMA (24 x 1KB chunks/step).
// LDS fp8 rows 64B; 16B-granule XOR involution (src (lane&3)^((lane>>2)&3), read ^(row&3)).
__global__ __launch_bounds__(512) void gemm2_kernel(const unsigned char* __restrict__ x8,
                                                    const unsigned char* __restrict__ Wt8,
                                                    const float* __restrict__ bias,
                                                    const float* __restrict__ gamma,
                                                    const float* __restrict__ beta,
                                                    float* __restrict__ outp) {
    __shared__ unsigned char As8[2][128 * 64];
    __shared__ unsigned char Bs8[2][256 * 64];
    __shared__ float rs[128][4];
    __shared__ float rss[128][4];
    const int tid = threadIdx.x;
    const int lane = tid & 63, wid = tid >> 6;
    const int wm = wid >> 2, wn = wid & 3;
    const int r = lane & 15, q = lane >> 4;
    const int m0 = blockIdx.x * 128;
    const int crow = lane >> 2;                                 // 16 rows/chunk, 4 lanes/row
    const int scol16 = (((lane & 3) ^ ((lane >> 2) & 3)) << 4); // pre-swizzled 16B src granule

    f32x4 acc[4][4] = {};

    auto stage = [&](int c, int kb) {
#pragma unroll
        for (int k = 0; k < 3; ++k) {
            int idx = 3 * wid + k;
            if (idx < 16) {
                int n = idx * 16 + crow;
                dma16(Wt8 + (size_t)n * KCAT + kb + scol16, &Bs8[c][idx * 1024]);
            } else {
                int a = idx - 16;
                int row = m0 + a * 16 + crow;   // tail reads past x8 land in ws: safe, store-guarded
                dma16(x8 + (size_t)row * KCAT + kb + scol16, &As8[c][a * 1024]);
            }
        }
    };

    // fragment read: row-major 64B rows, 16B granule swizzled by row&3
    auto lda = [&](const unsigned char* base, int row, int kk) -> long {
        int g16 = (kk * 2 + (q >> 1)) ^ (row & 3);
        return *(const long*)(base + row * 64 + g16 * 16 + (q & 1) * 8);
    };

    stage(0, 0);
    __syncthreads();

    for (int t = 0; t < 20; ++t) {
        const int c = t & 1;
        if (t < 19) stage(c ^ 1, (t + 1) * 64);
        long af[4][2], bfv[4][2];
#pragma unroll
        for (int am = 0; am < 4; ++am) {
            int row = wm * 64 + am * 16 + r;
            af[am][0] = lda(As8[c], row, 0);
            af[am][1] = lda(As8[c], row, 1);
        }
#pragma unroll
        for (int bn = 0; bn < 4; ++bn) {
            int row = wn * 64 + bn * 16 + r;
            bfv[bn][0] = lda(Bs8[c], row, 0);
            bfv[bn][1] = lda(Bs8[c], row, 1);
        }
#pragma unroll
        for (int kk = 0; kk < 2; ++kk)
#pragma unroll
            for (int am = 0; am < 4; ++am)
#pragma unroll
                for (int bn = 0; bn < 4; ++bn)
                    acc[am][bn] = mfma8(af[am][kk], bfv[bn][kk], acc[am][bn]);
        __syncthreads();
    }

    float bc[4], gm[4], bt[4];
#pragma unroll
    for (int bn = 0; bn < 4; ++bn) {
        int col = wn * 64 + bn * 16 + r;
        bc[bn] = bias[col];
        gm[bn] = gamma[col];
        bt[bn] = beta[col];
    }
#pragma unroll
    for (int am = 0; am < 4; ++am) {
#pragma unroll
        for (int i = 0; i < 4; ++i) {
            float s = 0.f, ss = 0.f;
#pragma unroll
            for (int bn = 0; bn < 4; ++bn) {
                float v = acc[am][bn][i] + bc[bn];
                v = 0.5f * v * (1.f + erff(v * 0.70710678118654752f));
                acc[am][bn][i] = v;
                s += v;
                ss += v * v;
            }
#pragma unroll
            for (int msk = 1; msk < 16; msk <<= 1) {
                s += __shfl_xor(s, msk);
                ss += __shfl_xor(ss, msk);
            }
            if (r == 0) {
                int row = wm * 64 + am * 16 + q * 4 + i;
                rs[row][wn] = s;
                rss[row][wn] = ss;
            }
        }
    }
    __syncthreads();
#pragma unroll
    for (int am = 0; am < 4; ++am) {
#pragma unroll
        for (int i = 0; i < 4; ++i) {
            int row = wm * 64 + am * 16 + q * 4 + i;
            float s = rs[row][0] + rs[row][1] + rs[row][2] + rs[row][3];
            float ss = rss[row][0] + rss[row][1] + rss[row][2] + rss[row][3];
            float mu = s * (1.f / HID);
            float var = ss * (1.f / HID) - mu * mu;
            float inv = rsqrtf(var + 1e-5f);
            if (m0 + row < NSEG) {
#pragma unroll
                for (int bn = 0; bn < 4; ++bn) {
                    int col = wn * 64 + bn * 16 + r;
                    outp[(size_t)(m0 + row) * HID + col] = (acc[am][bn][i] - mu) * inv * gm[bn] + bt[bn];
                }
            }
        }
    }
}

// ---------------------------------------------------------------- launch
extern "C" void kernel_launch(void* const* d_in, const int* in_sizes, int n_in,
                              void* d_out, int out_size, void* d_ws, size_t ws_size,
                              hipStream_t stream) {
    const float* P     = (const float*)d_in[0];
    const float* S     = (const float*)d_in[1];
    const void*  E     = d_in[2];
    const float* W     = (const float*)d_in[3];
    const float* bias  = (const float*)d_in[4];
    const float* gamma = (const float*)d_in[5];
    const float* beta  = (const float*)d_in[6];

    float* out = (float*)d_out;            // seg_low [40000*256]
    float* raw = out + (size_t)NSEG * HID; // seg_low_raw [40000*256]

    char* ws = (char*)d_ws;
    size_t off = 0;
    auto alloc = [&](size_t bytes) -> void* {
        void* p = ws + off;
        off += (bytes + 255) & ~(size_t)255;
        return p;
    };
    unsigned short* xcat   = (unsigned short*)alloc((size_t)NSEG * KCAT * 2);
    unsigned char*  x8     = (unsigned char*)alloc((size_t)NSEG * KCAT);
    unsigned short* Pt     = (unsigned short*)alloc((size_t)HID * KP1 * 2);
    unsigned char*  Wt8    = (unsigned char*)alloc((size_t)HID * KCAT);
    int*            deg    = (int*)alloc((size_t)NSEG * 4);
    float*          dinv   = (float*)alloc((size_t)NSEG * 4);
    int*            cnt    = (int*)alloc((size_t)NSEG * 4);
    int*            rowptr = (int*)alloc((size_t)(NSEG + 1) * 4);
    int*            cursor = (int*)alloc((size_t)NSEG * 4);
    long long*      colval = (long long*)alloc((size_t)NEDGE * 8);
    int*            bsum   = (int*)alloc((size_t)NBLK * 4);
    int*            boff   = (int*)alloc((size_t)NBLK * 4);
    int*            flag   = (int*)alloc(256);
    if (off > ws_size) return;

    hipMemsetAsync(deg, 0, (size_t)NSEG * 4, stream);
    hipMemsetAsync(cnt, 0, (size_t)NSEG * 4, stream);

    detect_kernel<<<1, 64, 0, stream>>>((const unsigned int*)E, flag);
    prep_w_kernel<<<HID, 256, 0, stream>>>(P, W, Pt, Wt8);

    deg_cnt_kernel<<<NEDGE / 256, 256, 0, stream>>>(E, flag, deg, cnt);
    scan1_kernel<<<NBLK, 256, 0, stream>>>(cnt, deg, dinv, bsum);
    scan2_kernel<<<1, 256, 0, stream>>>(bsum, boff, rowptr);
    scan3_kernel<<<NBLK, 256, 0, stream>>>(cnt, boff, rowptr, cursor);
    scatter_kernel<<<NEDGE / 256, 256, 0, stream>>>(E, flag, dinv, cursor, colval);

    gemm1_kernel<<<NSEG / 64, 256, 0, stream>>>(S, Pt, raw, xcat, x8);

    // bf16 out needed only where later used as subtraction operand (segs 1,2)
    prop_kernel<<<NSEG / 4, 256, 0, stream>>>(xcat, x8, rowptr, colval, 0 * HID, 1 * HID, -1, 1.f, 1);
    prop_kernel<<<NSEG / 4, 256, 0, stream>>>(xcat, x8, rowptr, colval, 1 * HID, 2 * HID, 0 * HID, 2.f, 1);
    prop_kernel<<<NSEG / 4, 256, 0, stream>>>(xcat, x8, rowptr, colval, 2 * HID, 3 * HID, 1 * HID, 2.f, 0);
    prop_kernel<<<NSEG / 4, 256, 0, stream>>>(xcat, x8, rowptr, colval, 3 * HID, 4 * HID, 2 * HID, 2.f, 0);

    gemm2_kernel<<<(NSEG + 127) / 128, 512, 0, stream>>>(x8, Wt8, bias, gamma, beta, out);
}

// Round 15
// 383.127 us; speedup vs baseline: 1.0191x; 1.0016x over previous
//
#include <hip/hip_runtime.h>

#define NSEG 40000
#define NREG 1000
#define NEDGE 640000
#define HID 256
#define KCAT 1280   // 5 * HID
#define KP1 1024    // padded K stride for Pt (cols 1000..1023 zero)
#define LPAD 40     // LDS row stride (bf16) for gemm1 tiles
#define LF8 72      // LDS row stride (bytes) for fp8 gemm2 tiles (18 banks -> conflict-free)
#define NBLK 157    // ceil(NSEG/256)

typedef float f32x4 __attribute__((ext_vector_type(4)));
typedef float f32x2 __attribute__((ext_vector_type(2)));
typedef short s16x8 __attribute__((ext_vector_type(8)));
typedef unsigned short u16x4 __attribute__((ext_vector_type(4)));
typedef unsigned short u16x8 __attribute__((ext_vector_type(8)));
typedef unsigned int u32x2 __attribute__((ext_vector_type(2)));
typedef unsigned int u32x4 __attribute__((ext_vector_type(4)));

__device__ __forceinline__ unsigned short f2bf(float f) {
    unsigned u = __builtin_bit_cast(unsigned, f);
    u += 0x7FFFu + ((u >> 16) & 1u);   // round-to-nearest-even
    return (unsigned short)(u >> 16);
}
__device__ __forceinline__ float bf2f(unsigned short h) {
    unsigned u = ((unsigned)h) << 16;
    return __builtin_bit_cast(float, u);
}
__device__ __forceinline__ unsigned char f2fp8(float v) {
    return (unsigned char)__builtin_amdgcn_cvt_pk_fp8_f32(v, v, 0, false);
}

__device__ __forceinline__ f32x4 mfma16(s16x8 a, s16x8 b, f32x4 c) {
    return __builtin_amdgcn_mfma_f32_16x16x32_bf16(a, b, c, 0, 0, 0);
}
__device__ __forceinline__ f32x4 mfma8(long a, long b, f32x4 c) {
    return __builtin_amdgcn_mfma_f32_16x16x32_fp8_fp8(a, b, c, 0, 0, 0);
}

// ---------------------------------------------------------------- edge dtype
__global__ void detect_kernel(const unsigned int* __restrict__ E, int* flag) {
    int lane = threadIdx.x;
    unsigned v = E[2 * lane + 1];
    unsigned long long m = __ballot(v == 0u);
    if (lane == 0) *flag = (__popcll(m) >= 48) ? 1 : 0;
}

__device__ __forceinline__ int edge_at(const void* E, int idx, int is64) {
    return is64 ? (int)((const long long*)E)[idx] : ((const int*)E)[idx];
}

// ---------------------------------------------------------------- CSR build
__global__ __launch_bounds__(256) void deg_cnt_kernel(const void* __restrict__ E,
                                                      const int* __restrict__ flag,
                                                      int* deg, int* cnt) {
    int e = blockIdx.x * 256 + threadIdx.x;
    if (e >= NEDGE) return;
    int is64 = *flag;
    int s = edge_at(E, e, is64);
    int d = edge_at(E, e + NEDGE, is64);
    if (s != d) {
        atomicAdd(&deg[s], 1);
        atomicAdd(&cnt[d], 1);
    }
}

// --- hierarchical scan (scan1 also computes dinv)
__global__ __launch_bounds__(256) void scan1_kernel(const int* __restrict__ cnt,
                                                    const int* __restrict__ deg,
                                                    float* __restrict__ dinv,
                                                    int* __restrict__ bsum) {
    __shared__ int sh[256];
    int t = threadIdx.x;
    int i = blockIdx.x * 256 + t;
    int c = (i < NSEG) ? cnt[i] : 0;
    sh[t] = c;
    if (i < NSEG) {
        int d = deg[i];
        dinv[i] = d > 0 ? rsqrtf((float)d) : 0.f;
    }
    __syncthreads();
    for (int o = 128; o > 0; o >>= 1) {
        if (t < o) sh[t] += sh[t + o];
        __syncthreads();
    }
    if (t == 0) bsum[blockIdx.x] = sh[0];
}

__global__ __launch_bounds__(256) void scan2_kernel(const int* __restrict__ bsum,
                                                    int* __restrict__ boff,
                                                    int* __restrict__ rowptr) {
    __shared__ int sh[256];
    int t = threadIdx.x;
    int v = (t < NBLK) ? bsum[t] : 0;
    sh[t] = v;
    __syncthreads();
    for (int o = 1; o < 256; o <<= 1) {
        int x = 0;
        if (t >= o) x = sh[t - o];
        __syncthreads();
        if (t >= o) sh[t] += x;
        __syncthreads();
    }
    if (t < NBLK) boff[t] = sh[t] - v;
    if (t == 255) rowptr[NSEG] = sh[255];
}

__global__ __launch_bounds__(256) void scan3_kernel(const int* __restrict__ cnt,
                                                    const int* __restrict__ boff,
                                                    int* __restrict__ rowptr,
                                                    int* __restrict__ cursor) {
    __shared__ int sh[256];
    int t = threadIdx.x;
    int i = blockIdx.x * 256 + t;
    int v = (i < NSEG) ? cnt[i] : 0;
    sh[t] = v;
    __syncthreads();
    for (int o = 1; o < 256; o <<= 1) {
        int x = 0;
        if (t >= o) x = sh[t - o];
        __syncthreads();
        if (t >= o) sh[t] += x;
        __syncthreads();
    }
    if (i < NSEG) {
        int p = boff[blockIdx.x] + sh[t] - v;
        rowptr[i] = p;
        cursor[i] = p;
    }
}

// writes fused (colidx, val-bits) 8B records
__global__ __launch_bounds__(256) void scatter_kernel(const void* __restrict__ E,
                                                      const int* __restrict__ flag,
                                                      const float* __restrict__ dinv,
                                                      int* cursor,
                                                      long long* __restrict__ colval) {
    int e = blockIdx.x * 256 + threadIdx.x;
    if (e >= NEDGE) return;
    int is64 = *flag;
    int s = edge_at(E, e, is64);
    int d = edge_at(E, e + NEDGE, is64);
    if (s != d) {
        int pos = atomicAdd(&cursor[d], 1);
        float v = -dinv[s] * dinv[d];
        colval[pos] = ((long long)(unsigned)__builtin_bit_cast(unsigned, v) << 32)
                    | (unsigned)s;
    }
}

// ---------------------------------------------------------------- weight prep
__global__ void prep_w_kernel(const float* __restrict__ P, const float* __restrict__ W,
                              unsigned short* __restrict__ Pt, unsigned char* __restrict__ Wt8) {
    int n = blockIdx.x;
    for (int k = threadIdx.x; k < KP1; k += blockDim.x)
        Pt[(size_t)n * KP1 + k] = (k < NREG) ? f2bf(P[(size_t)k * HID + n]) : (unsigned short)0;
    for (int k = threadIdx.x; k < KCAT; k += blockDim.x)
        Wt8[(size_t)n * KCAT + k] = f2fp8(W[(size_t)k * HID + n]);
}

// ---------------------------------------------------------------- GEMM1 (R9-exact structure: 93-96us)
__global__ __launch_bounds__(256) void gemm1_kernel(const float* __restrict__ S,
                                                    const unsigned short* __restrict__ Pt,
                                                    float* __restrict__ raw,
                                                    unsigned short* __restrict__ xcat,
                                                    unsigned char* __restrict__ x8) {
    __shared__ unsigned short As[64][LPAD];
    __shared__ unsigned short Bs[256][LPAD];
    const int m0 = blockIdx.x * 64;
    const int tid = threadIdx.x;
    const int lane = tid & 63, wn = tid >> 6;
    const int r = lane & 15, q = lane >> 4;
    const int srow = tid >> 2, scol = (tid & 3) * 8;

    f32x4 acc[4][4] = {};

    for (int kb = 0; kb < NREG; kb += 32) {
        const bool kvalid = (kb + scol + 8 <= NREG);  // NREG % 8 == 0
        u16x8 av = {0, 0, 0, 0, 0, 0, 0, 0};
        u16x8 bv0 = av, bv1 = av, bv2 = av, bv3 = av;
        if (kvalid) {
            const float* sp = S + (size_t)(m0 + srow) * NREG + kb + scol;
            f32x4 f0 = *(const f32x4*)sp;
            f32x4 f1 = *(const f32x4*)(sp + 4);
            av[0] = f2bf(f0[0]); av[1] = f2bf(f0[1]); av[2] = f2bf(f0[2]); av[3] = f2bf(f0[3]);
            av[4] = f2bf(f1[0]); av[5] = f2bf(f1[1]); av[6] = f2bf(f1[2]); av[7] = f2bf(f1[3]);
            bv0 = *(const u16x8*)(Pt + (size_t)(srow)       * KP1 + kb + scol);
            bv1 = *(const u16x8*)(Pt + (size_t)(srow +  64) * KP1 + kb + scol);
            bv2 = *(const u16x8*)(Pt + (size_t)(srow + 128) * KP1 + kb + scol);
            bv3 = *(const u16x8*)(Pt + (size_t)(srow + 192) * KP1 + kb + scol);
        }
        __syncthreads();
        *(u16x8*)&As[srow][scol] = av;
        *(u16x8*)&Bs[srow][scol] = bv0;
        *(u16x8*)&Bs[srow + 64][scol] = bv1;
        *(u16x8*)&Bs[srow + 128][scol] = bv2;
        *(u16x8*)&Bs[srow + 192][scol] = bv3;
        __syncthreads();
        s16x8 af[4], bfv[4];
#pragma unroll
        for (int am = 0; am < 4; ++am) af[am] = *(const s16x8*)&As[am * 16 + r][q * 8];
#pragma unroll
        for (int bn = 0; bn < 4; ++bn) bfv[bn] = *(const s16x8*)&Bs[wn * 64 + bn * 16 + r][q * 8];
#pragma unroll
        for (int am = 0; am < 4; ++am) {
#pragma unroll
            for (int bn = 0; bn < 4; ++bn)
                acc[am][bn] = mfma16(af[am], bfv[bn], acc[am][bn]);
        }
    }
#pragma unroll
    for (int am = 0; am < 4; ++am) {
        int rowb = m0 + am * 16 + q * 4;
#pragma unroll
        for (int bn = 0; bn < 4; ++bn) {
            int col = wn * 64 + bn * 16 + r;
#pragma unroll
            for (int i = 0; i < 4; ++i) {
                float v = acc[am][bn][i];
                raw[(size_t)(rowb + i) * HID + col] = v;
                xcat[(size_t)(rowb + i) * KCAT + col] = f2bf(v);
                x8[(size_t)(rowb + i) * KCAT + col] = f2fp8(v);
            }
        }
    }
}

// ---------------------------------------------------------------- propagation (half-wave, fp8 gather)
__global__ __launch_bounds__(256) void prop_kernel(unsigned short* xcat,
                                                   unsigned char* x8,
                                                   const int* __restrict__ rowptr,
                                                   const long long* __restrict__ colval,
                                                   int inOff, int outOff, int subOff,
                                                   float scale, int writeBf16) {
    const int g = blockIdx.x * 4 + (threadIdx.x >> 6);
    const int lane = threadIdx.x & 63;
    const int half = lane >> 5;
    const int l5 = lane & 31;
    const int e0 = rowptr[g], e1 = rowptr[g + 1];
    float a0 = 0.f, a1 = 0.f, a2 = 0.f, a3 = 0.f;
    float a4 = 0.f, a5 = 0.f, a6 = 0.f, a7 = 0.f;
    const unsigned char* xin = x8 + inOff + l5 * 8;

    for (int base = e0; base < e1; base += 64) {
        int m = e1 - base;
        if (m > 64) m = 64;
        int cc = 0;
        float vv = 0.f;
        if (lane < m) {
            long long cv = colval[base + lane];
            cc = (int)(unsigned)cv;
            vv = __builtin_bit_cast(float, (unsigned)(cv >> 32));
        }
        int i = 0;
#pragma unroll 4
        for (; i + 2 <= m; i += 2) {
            int c = __shfl(cc, i + half);
            float v = __shfl(vv, i + half);
            u32x2 t = *(const u32x2*)(xin + (size_t)c * KCAT);
            f32x2 d0 = __builtin_amdgcn_cvt_pk_f32_fp8(t[0], false);
            f32x2 d1 = __builtin_amdgcn_cvt_pk_f32_fp8(t[0], true);
            f32x2 d2 = __builtin_amdgcn_cvt_pk_f32_fp8(t[1], false);
            f32x2 d3 = __builtin_amdgcn_cvt_pk_f32_fp8(t[1], true);
            a0 += v * d0[0]; a1 += v * d0[1];
            a2 += v * d1[0]; a3 += v * d1[1];
            a4 += v * d2[0]; a5 += v * d2[1];
            a6 += v * d3[0]; a7 += v * d3[1];
        }
        if (i < m) {   // odd tail: half0 handles the last edge
            int c = __shfl(cc, i);
            float v = __shfl(vv, i);
            if (half == 0) {
                u32x2 t = *(const u32x2*)(xin + (size_t)c * KCAT);
                f32x2 d0 = __builtin_amdgcn_cvt_pk_f32_fp8(t[0], false);
                f32x2 d1 = __builtin_amdgcn_cvt_pk_f32_fp8(t[0], true);
                f32x2 d2 = __builtin_amdgcn_cvt_pk_f32_fp8(t[1], false);
                f32x2 d3 = __builtin_amdgcn_cvt_pk_f32_fp8(t[1], true);
                a0 += v * d0[0]; a1 += v * d0[1];
                a2 += v * d1[0]; a3 += v * d1[1];
                a4 += v * d2[0]; a5 += v * d2[1];
                a6 += v * d3[0]; a7 += v * d3[1];
            }
        }
    }
    a0 += __shfl_xor(a0, 32); a1 += __shfl_xor(a1, 32);
    a2 += __shfl_xor(a2, 32); a3 += __shfl_xor(a3, 32);
    a4 += __shfl_xor(a4, 32); a5 += __shfl_xor(a5, 32);
    a6 += __shfl_xor(a6, 32); a7 += __shfl_xor(a7, 32);

    if (half == 0) {
        a0 *= scale; a1 *= scale; a2 *= scale; a3 *= scale;
        a4 *= scale; a5 *= scale; a6 *= scale; a7 *= scale;
        if (subOff >= 0) {   // subtraction operand stays bf16 (accurate)
            u16x8 p = *(const u16x8*)(xcat + (size_t)g * KCAT + subOff + l5 * 8);
            a0 -= bf2f(p[0]); a1 -= bf2f(p[1]); a2 -= bf2f(p[2]); a3 -= bf2f(p[3]);
            a4 -= bf2f(p[4]); a5 -= bf2f(p[5]); a6 -= bf2f(p[6]); a7 -= bf2f(p[7]);
        }
        if (writeBf16) {
            u16x8 o = {f2bf(a0), f2bf(a1), f2bf(a2), f2bf(a3),
                       f2bf(a4), f2bf(a5), f2bf(a6), f2bf(a7)};
            *(u16x8*)(xcat + (size_t)g * KCAT + outOff + l5 * 8) = o;
        }
        unsigned p0 = 0, p1 = 0;
        p0 = __builtin_amdgcn_cvt_pk_fp8_f32(a0, a1, (int)p0, false);
        p0 = __builtin_amdgcn_cvt_pk_fp8_f32(a2, a3, (int)p0, true);
        p1 = __builtin_amdgcn_cvt_pk_fp8_f32(a4, a5, (int)p1, false);
        p1 = __builtin_amdgcn_cvt_pk_fp8_f32(a6, a7, (int)p1, true);
        u32x2 o8 = {p0, p1};
        *(u32x2*)(x8 + (size_t)g * KCAT + outOff + l5 * 8) = o8;
    }
}

// ---------------------------------------------------------------- GEMM2 fp8 (R9-gemm1 structure) + GELU + LN
// pre = X8 @ W8 + bias; out = LN(GELU(pre)).
// BM=64 BN=256 BK=64, 256 thr (4 waves over N), single-buffer 2-barrier,
// plain vector loads, 72B-padded fp8 LDS rows (conflict-free ds_read_b64), 20 iters.
__global__ __launch_bounds__(256) void gemm2_kernel(const unsigned char* __restrict__ x8,
                                                    const unsigned char* __restrict__ Wt8,
                                                    const float* __restrict__ bias,
                                                    const float* __restrict__ gamma,
                                                    const float* __restrict__ beta,
                                                    float* __restrict__ outp) {
    __shared__ unsigned char As8[64][LF8];
    __shared__ unsigned char Bs8[256][LF8];
    __shared__ float rs[64][4];
    __shared__ float rss[64][4];
    const int m0 = blockIdx.x * 64;
    const int tid = threadIdx.x;
    const int lane = tid & 63, wn = tid >> 6;
    const int r = lane & 15, q = lane >> 4;
    const int srow = tid >> 2, scol = (tid & 3) * 16;
    const unsigned char* aptr = x8 + (size_t)(m0 + srow) * KCAT;

    f32x4 acc[4][4] = {};

    for (int kb = 0; kb < KCAT; kb += 64) {
        u32x4 av = *(const u32x4*)(aptr + kb + scol);
        u32x4 bv[4];
#pragma unroll
        for (int j = 0; j < 4; ++j)
            bv[j] = *(const u32x4*)(Wt8 + (size_t)(j * 64 + srow) * KCAT + kb + scol);
        __syncthreads();
        *(u32x4*)&As8[srow][scol] = av;
#pragma unroll
        for (int j = 0; j < 4; ++j)
            *(u32x4*)&Bs8[j * 64 + srow][scol] = bv[j];
        __syncthreads();
        long af[4][2], bfv[4][2];
#pragma unroll
        for (int am = 0; am < 4; ++am) {
            af[am][0] = *(const long*)&As8[am * 16 + r][q * 8];
            af[am][1] = *(const long*)&As8[am * 16 + r][32 + q * 8];
        }
#pragma unroll
        for (int bn = 0; bn < 4; ++bn) {
            bfv[bn][0] = *(const long*)&Bs8[wn * 64 + bn * 16 + r][q * 8];
            bfv[bn][1] = *(const long*)&Bs8[wn * 64 + bn * 16 + r][32 + q * 8];
        }
#pragma unroll
        for (int kk = 0; kk < 2; ++kk)
#pragma unroll
            for (int am = 0; am < 4; ++am)
#pragma unroll
                for (int bn = 0; bn < 4; ++bn)
                    acc[am][bn] = mfma8(af[am][kk], bfv[bn][kk], acc[am][bn]);
    }

    // epilogue: bias + exact GELU, row stats, LN, store
    float bc[4], gm[4], bt[4];
#pragma unroll
    for (int bn = 0; bn < 4; ++bn) {
        int col = wn * 64 + bn * 16 + r;
        bc[bn] = bias[col];
        gm[bn] = gamma[col];
        bt[bn] = beta[col];
    }
#pragma unroll
    for (int am = 0; am < 4; ++am) {
#pragma unroll
        for (int i = 0; i < 4; ++i) {
            float s = 0.f, ss = 0.f;
#pragma unroll
            for (int bn = 0; bn < 4; ++bn) {
                float v = acc[am][bn][i] + bc[bn];
                v = 0.5f * v * (1.f + erff(v * 0.70710678118654752f));
                acc[am][bn][i] = v;
                s += v;
                ss += v * v;
            }
#pragma unroll
            for (int msk = 1; msk < 16; msk <<= 1) {
                s += __shfl_xor(s, msk);
                ss += __shfl_xor(ss, msk);
            }
            if (r == 0) {
                int row = am * 16 + q * 4 + i;
                rs[row][wn] = s;
                rss[row][wn] = ss;
            }
        }
    }
    __syncthreads();
#pragma unroll
    for (int am = 0; am < 4; ++am) {
#pragma unroll
        for (int i = 0; i < 4; ++i) {
            int row = am * 16 + q * 4 + i;
            float s = rs[row][0] + rs[row][1] + rs[row][2] + rs[row][3];
            float ss = rss[row][0] + rss[row][1] + rss[row][2] + rss[row][3];
            float mu = s * (1.f / HID);
            float var = ss * (1.f / HID) - mu * mu;
            float inv = rsqrtf(var + 1e-5f);
#pragma unroll
            for (int bn = 0; bn < 4; ++bn) {
                int col = wn * 64 + bn * 16 + r;
                outp[(size_t)(m0 + row) * HID + col] = (acc[am][bn][i] - mu) * inv * gm[bn] + bt[bn];
            }
        }
    }
}

// ---------------------------------------------------------------- launch
extern "C" void kernel_launch(void* const* d_in, const int* in_sizes, int n_in,
                              void* d_out, int out_size, void* d_ws, size_t ws_size,
                              hipStream_t stream) {
    const float* P     = (const float*)d_in[0];
    const float* S     = (const float*)d_in[1];
    const void*  E     = d_in[2];
    const float* W     = (const float*)d_in[3];
    const float* bias  = (const float*)d_in[4];
    const float* gamma = (const float*)d_in[5];
    const float* beta  = (const float*)d_in[6];

    float* out = (float*)d_out;            // seg_low [40000*256]
    float* raw = out + (size_t)NSEG * HID; // seg_low_raw [40000*256]

    char* ws = (char*)d_ws;
    size_t off = 0;
    auto alloc = [&](size_t bytes) -> void* {
        void* p = ws + off;
        off += (bytes + 255) & ~(size_t)255;
        return p;
    };
    unsigned short* xcat   = (unsigned short*)alloc((size_t)NSEG * KCAT * 2);
    unsigned char*  x8     = (unsigned char*)alloc((size_t)NSEG * KCAT);
    unsigned short* Pt     = (unsigned short*)alloc((size_t)HID * KP1 * 2);
    unsigned char*  Wt8    = (unsigned char*)alloc((size_t)HID * KCAT);
    int*            deg    = (int*)alloc((size_t)NSEG * 4);
    float*          dinv   = (float*)alloc((size_t)NSEG * 4);
    int*            cnt    = (int*)alloc((size_t)NSEG * 4);
    int*            rowptr = (int*)alloc((size_t)(NSEG + 1) * 4);
    int*            cursor = (int*)alloc((size_t)NSEG * 4);
    long long*      colval = (long long*)alloc((size_t)NEDGE * 8);
    int*            bsum   = (int*)alloc((size_t)NBLK * 4);
    int*            boff   = (int*)alloc((size_t)NBLK * 4);
    int*            flag   = (int*)alloc(256);
    if (off > ws_size) return;

    hipMemsetAsync(deg, 0, (size_t)NSEG * 4, stream);
    hipMemsetAsync(cnt, 0, (size_t)NSEG * 4, stream);

    detect_kernel<<<1, 64, 0, stream>>>((const unsigned int*)E, flag);
    prep_w_kernel<<<HID, 256, 0, stream>>>(P, W, Pt, Wt8);

    deg_cnt_kernel<<<NEDGE / 256, 256, 0, stream>>>(E, flag, deg, cnt);
    scan1_kernel<<<NBLK, 256, 0, stream>>>(cnt, deg, dinv, bsum);
    scan2_kernel<<<1, 256, 0, stream>>>(bsum, boff, rowptr);
    scan3_kernel<<<NBLK, 256, 0, stream>>>(cnt, boff, rowptr, cursor);
    scatter_kernel<<<NEDGE / 256, 256, 0, stream>>>(E, flag, dinv, cursor, colval);

    gemm1_kernel<<<NSEG / 64, 256, 0, stream>>>(S, Pt, raw, xcat, x8);

    // bf16 out needed only where later used as subtraction operand (segs 1,2)
    prop_kernel<<<NSEG / 4, 256, 0, stream>>>(xcat, x8, rowptr, colval, 0 * HID, 1 * HID, -1, 1.f, 1);
    prop_kernel<<<NSEG / 4, 256, 0, stream>>>(xcat, x8, rowptr, colval, 1 * HID, 2 * HID, 0 * HID, 2.f, 1);
    prop_kernel<<<NSEG / 4, 256, 0, stream>>>(xcat, x8, rowptr, colval, 2 * HID, 3 * HID, 1 * HID, 2.f, 0);
    prop_kernel<<<NSEG / 4, 256, 0, stream>>>(xcat, x8, rowptr, colval, 3 * HID, 4 * HID, 2 * HID, 2.f, 0);

    gemm2_kernel<<<NSEG / 64, 256, 0, stream>>>(x8, Wt8, bias, gamma, beta, out);
}